// Round 1
// baseline (444.629 us; speedup 1.0000x reference)
//
#include <hip/hip_runtime.h>
#include <math.h>

#define CHI 64
#define CHO 64
#define HH 128
#define WW 128
#define NB 4
#define KK 9
#define NOFF 27
#define EPSV 1e-5f

// ---------------- prep: weight transposes ----------------
// w_t[kk][ci][co]  = w[co][ci][kk]        (9*64*64 = 36864 floats)
// wo_t[ci][tap][c] = w_off[c][ci][tap]    (64*9*27 = 15552 floats)
__global__ __launch_bounds__(256) void prep_kernel(const float* __restrict__ w,
                                                   const float* __restrict__ w_off,
                                                   float* __restrict__ w_t,
                                                   float* __restrict__ wo_t) {
    int i = blockIdx.x * 256 + threadIdx.x;
    if (i < CHO * CHI * KK) {
        int kk = i / (CHI * CHO);
        int r  = i % (CHI * CHO);
        int ci = r / CHO;
        int co = r % CHO;
        w_t[i] = w[(co * CHI + ci) * KK + kk];
    }
    if (i < CHI * KK * NOFF) {
        int ci  = i / (KK * NOFF);
        int r   = i % (KK * NOFF);
        int tap = r / NOFF;
        int c   = r % NOFF;
        wo_t[i] = w_off[(c * CHI + ci) * KK + tap];
    }
}

// ---------------- offset conv: off[b][c][h][w], c in [0,27) ----------------
__global__ __launch_bounds__(128) void off_conv_kernel(const float* __restrict__ x,
                                                       const float* __restrict__ wo_t,
                                                       const float* __restrict__ b_off,
                                                       float* __restrict__ off) {
    const int h = blockIdx.x;
    const int b = blockIdx.y;
    const int w = threadIdx.x;

    float acc[NOFF];
#pragma unroll
    for (int c = 0; c < NOFF; c++) acc[c] = 0.f;

    const float* xb = x + (size_t)b * CHI * HH * WW;

    for (int ci = 0; ci < CHI; ci++) {
        const float* plane = xb + ci * HH * WW;
#pragma unroll
        for (int ky = 0; ky < 3; ky++) {
            int hr = h - 1 + ky;
            if (hr < 0 || hr >= HH) continue;   // wave-uniform branch
#pragma unroll
            for (int kx = 0; kx < 3; kx++) {
                int wc = w - 1 + kx;
                float xv = ((unsigned)wc < WW) ? plane[hr * WW + wc] : 0.f;
                const float* wp = wo_t + (ci * KK + ky * 3 + kx) * NOFF; // uniform -> s_load
#pragma unroll
                for (int c = 0; c < NOFF; c++) acc[c] = fmaf(xv, wp[c], acc[c]);
            }
        }
    }

#pragma unroll
    for (int c = 0; c < NOFF; c++)
        off[(((size_t)b * NOFF + c) * HH + h) * WW + w] = acc[c] + b_off[c];
}

// ---------------- deform sample + main conv ----------------
// grid (2, H, B); block 128 threads (one pixel each); 32 output channels/block
__global__ __launch_bounds__(128) void deform_kernel(const float* __restrict__ x,
                                                     const float* __restrict__ w_t,
                                                     const float* __restrict__ off,
                                                     const float* __restrict__ bias,
                                                     float* __restrict__ out) {
    const int co_base = blockIdx.x * 32;
    const int h = blockIdx.y;
    const int b = blockIdx.z;
    const int w = threadIdx.x;

    float acc[32];
#pragma unroll
    for (int j = 0; j < 32; j++) acc[j] = 0.f;

    const float* xb   = x + (size_t)b * CHI * HH * WW;
    const float* offb = off + (size_t)b * NOFF * HH * WW;

#pragma unroll
    for (int kk = 0; kk < KK; kk++) {
        const int ky = kk / 3, kx = kk % 3;
        float dy = offb[((2 * kk) * HH + h) * WW + w];
        float dx = offb[((2 * kk + 1) * HH + h) * WW + w];
        float mo = offb[((18 + kk) * HH + h) * WW + w];
        float m  = 1.f / (1.f + __expf(-mo));

        float py = (float)(h - 1 + ky) + dy;
        float px = (float)(w - 1 + kx) + dx;
        float fy0 = floorf(py), fx0 = floorf(px);
        float wy = py - fy0, wx = px - fx0;
        int y0 = (int)fy0, x0 = (int)fx0;
        int y1 = y0 + 1, x1 = x0 + 1;
        bool vy0 = (unsigned)y0 < HH, vy1 = (unsigned)y1 < HH;
        bool vx0 = (unsigned)x0 < WW, vx1 = (unsigned)x1 < WW;
        int cy0 = min(max(y0, 0), HH - 1), cy1 = min(max(y1, 0), HH - 1);
        int cx0 = min(max(x0, 0), WW - 1), cx1 = min(max(x1, 0), WW - 1);
        int i00 = cy0 * WW + cx0, i01 = cy0 * WW + cx1;
        int i10 = cy1 * WW + cx0, i11 = cy1 * WW + cx1;
        float a00 = (vy0 && vx0) ? (1.f - wy) * (1.f - wx) * m : 0.f;
        float a01 = (vy0 && vx1) ? (1.f - wy) * wx * m : 0.f;
        float a10 = (vy1 && vx0) ? wy * (1.f - wx) * m : 0.f;
        float a11 = (vy1 && vx1) ? wy * wx * m : 0.f;

        const float* wk = w_t + ((size_t)kk * CHI) * CHO + co_base;
        for (int ci = 0; ci < CHI; ci++) {
            const float* plane = xb + ci * HH * WW;
            float val = a00 * plane[i00] + a01 * plane[i01]
                      + a10 * plane[i10] + a11 * plane[i11];
            const float* wp = wk + ci * CHO;   // uniform -> s_load_dwordx*
#pragma unroll
            for (int j = 0; j < 32; j++) acc[j] = fmaf(val, wp[j], acc[j]);
        }
    }

#pragma unroll
    for (int j = 0; j < 32; j++) {
        int co = co_base + j;
        out[(((size_t)b * CHO + co) * HH + h) * WW + w] = acc[j] + bias[co];
    }
}

// ---------------- per-channel stats (sum, sumsq) ----------------
__global__ __launch_bounds__(256) void stats_kernel(const float* __restrict__ y,
                                                    float* __restrict__ stats) {
    const int co = blockIdx.x;
    const int b  = blockIdx.y;
    const float* p = y + ((size_t)b * CHO + co) * HH * WW;
    float s = 0.f, s2 = 0.f;
    for (int i = threadIdx.x; i < HH * WW; i += 256) {
        float v = p[i];
        s += v;
        s2 += v * v;
    }
#pragma unroll
    for (int o = 32; o > 0; o >>= 1) {
        s  += __shfl_down(s, o, 64);
        s2 += __shfl_down(s2, o, 64);
    }
    __shared__ float ls[4], ls2[4];
    int lane = threadIdx.x & 63, wv = threadIdx.x >> 6;
    if (lane == 0) { ls[wv] = s; ls2[wv] = s2; }
    __syncthreads();
    if (threadIdx.x == 0) {
        float ts = 0.f, t2 = 0.f;
#pragma unroll
        for (int i = 0; i < 4; i++) { ts += ls[i]; t2 += ls2[i]; }
        atomicAdd(&stats[co], ts);
        atomicAdd(&stats[64 + co], t2);
    }
}

// ---------------- BN + ReLU, in place on d_out ----------------
__global__ __launch_bounds__(256) void bn_kernel(float* __restrict__ y,
                                                 const float* __restrict__ stats,
                                                 const float* __restrict__ gamma,
                                                 const float* __restrict__ beta) {
    size_t base = (size_t)blockIdx.x * 1024;           // 16 blocks per (b,co) plane
    int co = (int)((base >> 14) & 63);                 // plane = base/16384; co = plane & 63
    const float inv_n = 1.f / 65536.f;
    float mean = stats[co] * inv_n;
    float var  = stats[64 + co] * inv_n - mean * mean;
    float sc = gamma[co] * rsqrtf(var + EPSV);
    float sh = beta[co] - mean * sc;
    float4* p = (float4*)(y + base);
    float4 v = p[threadIdx.x];
    v.x = fmaxf(fmaf(v.x, sc, sh), 0.f);
    v.y = fmaxf(fmaf(v.y, sc, sh), 0.f);
    v.z = fmaxf(fmaf(v.z, sc, sh), 0.f);
    v.w = fmaxf(fmaf(v.w, sc, sh), 0.f);
    p[threadIdx.x] = v;
}

extern "C" void kernel_launch(void* const* d_in, const int* in_sizes, int n_in,
                              void* d_out, int out_size, void* d_ws, size_t ws_size,
                              hipStream_t stream) {
    const float* x     = (const float*)d_in[0];
    const float* w_off = (const float*)d_in[1];
    const float* b_off = (const float*)d_in[2];
    const float* wmat  = (const float*)d_in[3];
    const float* bvec  = (const float*)d_in[4];
    const float* gamma = (const float*)d_in[5];
    const float* beta  = (const float*)d_in[6];
    float* out = (float*)d_out;

    char* ws = (char*)d_ws;
    float* stats = (float*)ws;                           // 512 B (sum[64], sumsq[64])
    float* w_t   = (float*)(ws + 1024);                  // 147456 B
    float* wo_t  = (float*)(ws + 1024 + 147456);         // 62208 B
    float* off   = (float*)(ws + 1024 + 147456 + 62208); // 7077888 B, offset 210688 (256-aligned)

    hipMemsetAsync(stats, 0, 512, stream);
    prep_kernel<<<(CHO * CHI * KK + 255) / 256, 256, 0, stream>>>(wmat, w_off, w_t, wo_t);
    off_conv_kernel<<<dim3(HH, NB), 128, 0, stream>>>(x, wo_t, b_off, off);
    deform_kernel<<<dim3(2, HH, NB), 128, 0, stream>>>(x, w_t, off, bvec, out);
    stats_kernel<<<dim3(CHO, NB), 256, 0, stream>>>(out, stats);
    bn_kernel<<<4096, 256, 0, stream>>>(out, stats, gamma, beta);
}

// Round 2
// 269.308 us; speedup vs baseline: 1.6510x; 1.6510x over previous
//
#include <hip/hip_runtime.h>
#include <math.h>

#define CHI 64
#define CHO 64
#define HH 128
#define WW 128
#define NB 4
#define KK 9
#define NOFF 27
#define EPSV 1e-5f
#define PLANE (HH * WW)
#define OFFCH ((size_t)NB * NOFF * PLANE)  // elements in one partial-offset chunk

// 2-float vector with only 4-byte alignment guarantee (bilinear pair loads)
typedef float f2v __attribute__((ext_vector_type(2), aligned(4)));

// ---------------- prep: weight transposes ----------------
// w_t[kk][ci][co]  = w[co][ci][kk]        (9*64*64 = 36864 floats)
// wo_t[ci][tap][c] = w_off[c][ci][tap]    (64*9*27 = 15552 floats)
__global__ __launch_bounds__(256) void prep_kernel(const float* __restrict__ w,
                                                   const float* __restrict__ w_off,
                                                   float* __restrict__ w_t,
                                                   float* __restrict__ wo_t) {
    int i = blockIdx.x * 256 + threadIdx.x;
    if (i < CHO * CHI * KK) {
        int kk = i / (CHI * CHO);
        int r  = i % (CHI * CHO);
        int ci = r / CHO;
        int co = r % CHO;
        w_t[i] = w[(co * CHI + ci) * KK + kk];
    }
    if (i < CHI * KK * NOFF) {
        int ci  = i / (KK * NOFF);
        int r   = i % (KK * NOFF);
        int tap = r / NOFF;
        int c   = r % NOFF;
        wo_t[i] = w_off[(c * CHI + ci) * KK + tap];
    }
}

// ---------------- offset conv, ci-chunked partials ----------------
// grid: 1024 blocks linear. blockIdx%8 -> (b, chunk) so each XCD (heuristic
// round-robin) sees one batch's 32 planes = 2 MB, L2-resident.
// offp[chunk][b][c][h][w], c in [0,27), NO b_off added (folded into deform).
__global__ __launch_bounds__(128) void off_conv_kernel(const float* __restrict__ x,
                                                       const float* __restrict__ wo_t,
                                                       float* __restrict__ offp) {
    const int id    = blockIdx.x;
    const int slot  = id & 7;
    const int b     = slot >> 1;
    const int chunk = slot & 1;
    const int h     = id >> 3;           // 0..127
    const int w     = threadIdx.x;

    float acc[NOFF];
#pragma unroll
    for (int c = 0; c < NOFF; c++) acc[c] = 0.f;

    const float* xb  = x + ((size_t)b * CHI + chunk * 32) * PLANE;
    const float* wob = wo_t + chunk * 32 * KK * NOFF;

    for (int ci = 0; ci < 32; ci++) {
        const float* plane = xb + ci * PLANE;
#pragma unroll
        for (int ky = 0; ky < 3; ky++) {
            int hr = h - 1 + ky;
            if (hr < 0 || hr >= HH) continue;   // wave-uniform branch
#pragma unroll
            for (int kx = 0; kx < 3; kx++) {
                int wc = w - 1 + kx;
                float xv = ((unsigned)wc < WW) ? plane[hr * WW + wc] : 0.f;
                const float* wp = wob + (ci * KK + ky * 3 + kx) * NOFF; // uniform -> s_load
#pragma unroll
                for (int c = 0; c < NOFF; c++) acc[c] = fmaf(xv, wp[c], acc[c]);
            }
        }
    }

#pragma unroll
    for (int c = 0; c < NOFF; c++)
        offp[chunk * OFFCH + (((size_t)b * NOFF + c) * HH + h) * WW + w] = acc[c];
}

// ---------------- deform sample + main conv ----------------
// grid: 512 blocks linear, 256 threads (2 rows x 128 px).
// blockIdx%8 -> (b, co_half): each XCD works one batch (x = 4MB = one L2).
__global__ __launch_bounds__(256) void deform_kernel(const float* __restrict__ x,
                                                     const float* __restrict__ w_t,
                                                     const float* __restrict__ offp,
                                                     const float* __restrict__ b_off,
                                                     const float* __restrict__ bias,
                                                     float* __restrict__ out) {
    const int id      = blockIdx.x;
    const int slot    = id & 7;
    const int b       = slot >> 1;
    const int co_base = (slot & 1) * 32;
    const int hp      = id >> 3;                       // 0..63
    const int h       = hp * 2 + (threadIdx.x >> 7);
    const int w       = threadIdx.x & 127;

    float acc[32];
#pragma unroll
    for (int j = 0; j < 32; j++) acc[j] = 0.f;

    const float* xb  = x + (size_t)b * CHI * PLANE;
    const float* op0 = offp + (size_t)b * NOFF * PLANE + h * WW + w;
    const float* op1 = op0 + OFFCH;

#pragma unroll
    for (int kk = 0; kk < KK; kk++) {
        const int ky = kk / 3, kx = kk % 3;
        float dy = op0[(2 * kk) * PLANE]     + op1[(2 * kk) * PLANE]     + b_off[2 * kk];
        float dx = op0[(2 * kk + 1) * PLANE] + op1[(2 * kk + 1) * PLANE] + b_off[2 * kk + 1];
        float mo = op0[(18 + kk) * PLANE]    + op1[(18 + kk) * PLANE]    + b_off[18 + kk];
        float m  = 1.f / (1.f + __expf(-mo));

        float py = (float)(h - 1 + ky) + dy;
        float px = (float)(w - 1 + kx) + dx;
        float fy0 = floorf(py), fx0 = floorf(px);
        float wy = py - fy0, wx = px - fx0;
        int y0 = (int)fy0, x0 = (int)fx0;
        int y1 = y0 + 1, x1 = x0 + 1;
        bool vy0 = (unsigned)y0 < HH, vy1 = (unsigned)y1 < HH;
        bool vx0 = (unsigned)x0 < WW, vx1 = (unsigned)x1 < WW;
        float a00 = (vy0 && vx0) ? (1.f - wy) * (1.f - wx) * m : 0.f;
        float a01 = (vy0 && vx1) ? (1.f - wy) * wx * m : 0.f;
        float a10 = (vy1 && vx0) ? wy * (1.f - wx) * m : 0.f;
        float a11 = (vy1 && vx1) ? wy * wx * m : 0.f;

        // column-pair trick: load (xbc, xbc+1) as one dwordx2; fold the
        // boundary column-select into the weights (once per kk, not per ci)
        int xbc = min(max(x0, 0), WW - 2);
        bool sel = (x0 == xbc);
        float c00 = sel ? a00 : a01, c01 = sel ? a01 : a00;
        float c10 = sel ? a10 : a11, c11 = sel ? a11 : a10;
        int cy0 = min(max(y0, 0), HH - 1), cy1 = min(max(y1, 0), HH - 1);
        const int o0 = cy0 * WW + xbc;
        const int o1 = cy1 * WW + xbc;

        const float* pl = xb;
        const float* wk = w_t + ((size_t)kk * CHI) * CHO + co_base;
#pragma unroll 2
        for (int ci = 0; ci < CHI; ci++) {
            f2v p0 = *(const f2v*)(pl + o0);
            f2v p1 = *(const f2v*)(pl + o1);
            float val = p0.x * c00 + p0.y * c01 + p1.x * c10 + p1.y * c11;
            const float* wp = wk + ci * CHO;   // wave-uniform -> s_load_dwordx16
#pragma unroll
            for (int j = 0; j < 32; j++) acc[j] = fmaf(val, wp[j], acc[j]);
            pl += PLANE;
        }
    }

#pragma unroll
    for (int j = 0; j < 32; j++) {
        int co = co_base + j;
        out[(((size_t)b * CHO + co) * HH + h) * WW + w] = acc[j] + bias[co];
    }
}

// ---------------- per-channel stats (sum, sumsq) ----------------
__global__ __launch_bounds__(256) void stats_kernel(const float* __restrict__ y,
                                                    float* __restrict__ stats) {
    const int co = blockIdx.x;
    const int b  = blockIdx.y;
    const float4* p4 = (const float4*)(y + ((size_t)b * CHO + co) * PLANE);
    float s = 0.f, s2 = 0.f;
    for (int i = threadIdx.x; i < PLANE / 4; i += 256) {
        float4 v = p4[i];
        s  += v.x + v.y + v.z + v.w;
        s2 += v.x * v.x + v.y * v.y + v.z * v.z + v.w * v.w;
    }
#pragma unroll
    for (int o = 32; o > 0; o >>= 1) {
        s  += __shfl_down(s, o, 64);
        s2 += __shfl_down(s2, o, 64);
    }
    __shared__ float ls[4], ls2[4];
    int lane = threadIdx.x & 63, wv = threadIdx.x >> 6;
    if (lane == 0) { ls[wv] = s; ls2[wv] = s2; }
    __syncthreads();
    if (threadIdx.x == 0) {
        float ts = 0.f, t2 = 0.f;
#pragma unroll
        for (int i = 0; i < 4; i++) { ts += ls[i]; t2 += ls2[i]; }
        atomicAdd(&stats[co], ts);
        atomicAdd(&stats[64 + co], t2);
    }
}

// ---------------- BN + ReLU, in place on d_out ----------------
__global__ __launch_bounds__(256) void bn_kernel(float* __restrict__ y,
                                                 const float* __restrict__ stats,
                                                 const float* __restrict__ gamma,
                                                 const float* __restrict__ beta) {
    size_t base = (size_t)blockIdx.x * 1024;           // 16 blocks per (b,co) plane
    int co = (int)((base >> 14) & 63);
    const float inv_n = 1.f / 65536.f;
    float mean = stats[co] * inv_n;
    float var  = stats[64 + co] * inv_n - mean * mean;
    float sc = gamma[co] * rsqrtf(var + EPSV);
    float sh = beta[co] - mean * sc;
    float4* p = (float4*)(y + base);
    float4 v = p[threadIdx.x];
    v.x = fmaxf(fmaf(v.x, sc, sh), 0.f);
    v.y = fmaxf(fmaf(v.y, sc, sh), 0.f);
    v.z = fmaxf(fmaf(v.z, sc, sh), 0.f);
    v.w = fmaxf(fmaf(v.w, sc, sh), 0.f);
    p[threadIdx.x] = v;
}

extern "C" void kernel_launch(void* const* d_in, const int* in_sizes, int n_in,
                              void* d_out, int out_size, void* d_ws, size_t ws_size,
                              hipStream_t stream) {
    const float* x     = (const float*)d_in[0];
    const float* w_off = (const float*)d_in[1];
    const float* b_off = (const float*)d_in[2];
    const float* wmat  = (const float*)d_in[3];
    const float* bvec  = (const float*)d_in[4];
    const float* gamma = (const float*)d_in[5];
    const float* beta  = (const float*)d_in[6];
    float* out = (float*)d_out;

    char* ws = (char*)d_ws;
    float* stats = (float*)ws;                           // 512 B
    float* w_t   = (float*)(ws + 1024);                  // 147456 B
    float* wo_t  = (float*)(ws + 1024 + 147456);         // 62208 B
    float* offp  = (float*)(ws + 210688);                // 2 chunks x 7077888 B

    hipMemsetAsync(stats, 0, 512, stream);
    prep_kernel<<<(CHO * CHI * KK + 255) / 256, 256, 0, stream>>>(wmat, w_off, w_t, wo_t);
    off_conv_kernel<<<1024, 128, 0, stream>>>(x, wo_t, offp);
    deform_kernel<<<512, 256, 0, stream>>>(x, w_t, offp, b_off, bvec, out);
    stats_kernel<<<dim3(CHO, NB), 256, 0, stream>>>(out, stats);
    bn_kernel<<<4096, 256, 0, stream>>>(out, stats, gamma, beta);
}